// Round 5
// baseline (3188.318 us; speedup 1.0000x reference)
//
#include <hip/hip_runtime.h>

typedef unsigned long long ull;
typedef _Float16 half2v __attribute__((ext_vector_type(2)));

#define B_ 64
#define T_ 1024
#define I_ 16
#define H_ 512
#define O_ 3
#define NIN_ 103
#define NEX_ 409

#define NQ 8    // blocks per batch cluster (64 rows each)
#define RS 64   // rows per block
#define SLOTS 40  // ull slots per (b,parity,q): 0-31 h f16x2, 32-34 tails
#define REC_ULL ((size_t)B_ * 2 * NQ * SLOTS)
#define FLAGS_OFF (REC_ULL * 8)
#define WS_NEED (FLAGS_OFF + (size_t)B_ * NQ * 4)

#define AL(p) __hip_atomic_load((p), __ATOMIC_RELAXED, __HIP_MEMORY_SCOPE_AGENT)
#define AS(p, v) \
  __hip_atomic_store((p), (v), __ATOMIC_RELAXED, __HIP_MEMORY_SCOPE_AGENT)

__device__ __forceinline__ float dot2(unsigned a, unsigned b, float c) {
  return __builtin_amdgcn_fdot2(__builtin_bit_cast(half2v, a),
                                __builtin_bit_cast(half2v, b), c, false);
}

// ---------------------------------------------------------------------------
// 8-block-per-batch cluster RNN. Block (b,q) owns rows [q*64, q*64+64) of
// W_h2h, held as f16 pairs in 16 VGPRs per thread (thread (w,l): row l,
// k in [w*32, w*32+32)). Exchange: tag-in-word 8-B relaxed agent atomics
// {f16x2 h, step tag} -> single L3 round trip, no fences, no flag trip.
// Flags are backpressure-only (depth-2 parity overwrite protection), off
// the critical path. 512 blocks x 1024 thr = 2 blocks/CU, co-resident by
// thread capacity (2048/CU); __launch_bounds__(1024,8) caps VGPR at 64.
// ---------------------------------------------------------------------------
__global__ __launch_bounds__(1024, 8) void rnn8(
    const float* __restrict__ x, const float* __restrict__ noise,
    const float* __restrict__ W_i2h, const float* __restrict__ b_i2h,
    const float* __restrict__ W_h2h, const float* __restrict__ b_h2h,
    const float* __restrict__ W_h2o, const float* __restrict__ b_h2o,
    const int* __restrict__ taup, const int* __restrict__ dtp,
    ull* __restrict__ recs, int* __restrict__ flags,
    float* __restrict__ out_net, float* __restrict__ out_rnn) {
  __shared__ unsigned h_lds[H_ / 2];    // 256 words: h(t) as f16x2
  __shared__ float partial_s[16 * RS];  // [wave][row]
  __shared__ float wi2h_s[RS * 17];     // padded W_i2h rows
  __shared__ float bias_s[RS];          // b_i2h + b_h2h
  __shared__ float x_s[I_];
  __shared__ float xi_s[RS];
  __shared__ float tails_s[21];

  const int tid = threadIdx.x;
  const int g = blockIdx.x;
  const int b = (g >> 6) * 8 + (g & 7);  // cluster blocks share g&7 (XCD)
  const int q = (g >> 3) & 7;
  const int wv = tid >> 6, ln = tid & 63;
  const int row0 = q * RS;

  const float alpha = (float)dtp[0] / (float)taup[0];
  const float nzscale = (float)(sqrt(2.0 * (double)alpha) * 0.01);

  // ---- W_h2h slice -> 16 VGPRs/thread, converted fp32 -> f16 in-kernel ----
  unsigned wreg[16];
  {
    const float* wrow = W_h2h + (size_t)(row0 + ln) * H_ + wv * 32;
#pragma unroll
    for (int i = 0; i < 8; ++i) {
      const float4 f = ((const float4*)wrow)[i];
      half2v lo = {(_Float16)f.x, (_Float16)f.y};
      half2v hi = {(_Float16)f.z, (_Float16)f.w};
      wreg[2 * i] = __builtin_bit_cast(unsigned, lo);
      wreg[2 * i + 1] = __builtin_bit_cast(unsigned, hi);
    }
  }
  // ---- other setup ----
  {
    const int l = tid >> 4, i = tid & 15;  // 1024 threads = 64 x 16 exactly
    wi2h_s[l * 17 + i] = W_i2h[(size_t)(row0 + l) * I_ + i];
  }
  if (tid < RS) bias_s[tid] = b_i2h[row0 + tid] + b_h2h[row0 + tid];
  if (tid < H_ / 2) h_lds[tid] = 0u;
  if (tid < RS) out_rnn[(size_t)b * (T_ + 1) * H_ + row0 + tid] = 0.f;
  if (q == 0 && tid >= RS && tid < RS + O_)
    out_net[(size_t)b * (T_ + 1) * O_ + (tid - RS)] = 0.f;
  float w30 = 0.f, w31 = 0.f, w32 = 0.f, bo = 0.f;
  if (wv == 0 && row0 + ln >= NIN_) {
    const int e = row0 + ln - NIN_;
    w30 = W_h2o[e];
    w31 = W_h2o[NEX_ + e];
    w32 = W_h2o[2 * NEX_ + e];
  }
  if (q == 0 && wv == 15 && ln < O_) bo = b_h2o[ln];
  __syncthreads();

  const size_t xrow = (size_t)b * T_ * I_;
  const size_t nrow = (size_t)b * T_ * H_ + row0;
  const int fb = b * NQ;
  const int pollp = wv >> 1;  // source block for this wave's k-chunk
  const bool dopoll = (pollp != q);

  float nzv = 0.f;
  for (int t = 0; t < T_; ++t) {
    // ---------- prologue: per-step loads + tag-polls ----------
    if (wv == 0) nzv = noise[nrow + (size_t)t * H_ + ln];
    if (wv == 2 * q + 1) {  // own-chunk wave (never polls): x load + xi
      if (ln < I_) x_s[ln] = x[xrow + (size_t)t * I_ + ln];
      __asm__ volatile("s_waitcnt vmcnt(0) lgkmcnt(0)" ::: "memory");
      float a = bias_s[ln];
#pragma unroll
      for (int i = 0; i < I_; ++i) a += wi2h_s[ln * 17 + i] * x_s[i];
      xi_s[ln] = a;
    }
    if (t > 0) {
      if (dopoll && ln < 16) {
        const ull* src = recs +
                         ((size_t)(b * 2 + (t & 1)) * NQ + pollp) * SLOTS +
                         (wv & 1) * 16 + ln;
        ull v;
        do { v = AL(src); } while ((unsigned)(v >> 32) != (unsigned)t);
        h_lds[wv * 16 + ln] = (unsigned)v;
      }
      if (q == 0 && wv == 15 && ln >= 16 && ln < 37) {
        const int i = ln - 16;
        const ull* srcT = recs +
                          ((size_t)(b * 2 + (t & 1)) * NQ + (1 + i / 3)) * SLOTS +
                          32 + i % 3;
        ull v;
        do { v = AL(srcT); } while ((unsigned)(v >> 32) != (unsigned)t);
        tails_s[i] = __uint_as_float((unsigned)v);
      }
    }
    __syncthreads();  // A: h(t) staged in h_lds
    if (t > 0 && tid == 1023) AS(&flags[fb + q], t);  // consumed tag-t
    if (t > 0 && q == 0 && wv == 15 && ln < O_) {     // out_net[b][t]
      float v = bo;
#pragma unroll
      for (int p3 = 0; p3 < 7; ++p3) v += tails_s[p3 * 3 + ln];
      out_net[((size_t)b * (T_ + 1) + t) * O_ + ln] = v;
    }
    // ---------- GEMV: pure-VALU dot2 from W-regs, h broadcast from LDS ----
    float acc = 0.f;
    const unsigned* hw = &h_lds[wv * 16];
#pragma unroll
    for (int i4 = 0; i4 < 4; ++i4) {
      const uint4 hv = ((const uint4*)hw)[i4];
      acc = dot2(wreg[i4 * 4 + 0], hv.x, acc);
      acc = dot2(wreg[i4 * 4 + 1], hv.y, acc);
      acc = dot2(wreg[i4 * 4 + 2], hv.z, acc);
      acc = dot2(wreg[i4 * 4 + 3], hv.w, acc);
    }
    partial_s[wv * RS + ln] = acc;
    __syncthreads();  // B: partials ready
    // ---------- epilogue (wave 0) ----------
    if (wv == 0) {
      float sum = 0.f;
#pragma unroll
      for (int w2 = 0; w2 < 16; ++w2) sum += partial_s[w2 * RS + ln];
      const float pre = alpha * (sum + xi_s[ln]) + nzscale * nzv;
      const float h = fmaxf(pre, 0.f);
      out_rnn[((size_t)b * (T_ + 1) + t + 1) * H_ + row0 + ln] = h;
      ((unsigned short*)h_lds)[row0 + ln] =
          __builtin_bit_cast(unsigned short, (_Float16)h);
      float p0 = h * w30, p1 = h * w31, p2 = h * w32;
#pragma unroll
      for (int off = 32; off >= 1; off >>= 1) {
        p0 += __shfl_xor(p0, off, 64);
        p1 += __shfl_xor(p1, off, 64);
        p2 += __shfl_xor(p2, off, 64);
      }
      if (ln < 7) {  // backpressure: peers consumed tag t-1 (provably near-
        const int peer = ln + (ln >= q ? 1 : 0);  // instant; overwrite guard)
        while (AL(&flags[fb + peer]) < t - 1) __builtin_amdgcn_s_sleep(1);
      }
      __asm__ volatile("s_waitcnt lgkmcnt(0)" ::: "memory");
      ull* dst = recs + ((size_t)(b * 2 + ((t + 1) & 1)) * NQ + q) * SLOTS;
      const ull tag = ((ull)(unsigned)(t + 1)) << 32;
      if (ln < 32) {
        AS(dst + ln, tag | (ull)h_lds[q * 32 + ln]);
      } else if (ln < 35) {
        const float pv = (ln == 32) ? p0 : (ln == 33) ? p1 : p2;
        AS(dst + ln, tag | (ull)__float_as_uint(pv));
      }
    }
  }
  // ---------- final out_net[b][T] ----------
  if (q == 0 && wv == 15) {
    if (ln >= 16 && ln < 37) {
      const int i = ln - 16;
      const ull* srcT = recs +
                        ((size_t)(b * 2 + (T_ & 1)) * NQ + (1 + i / 3)) * SLOTS +
                        32 + i % 3;
      ull v;
      do { v = AL(srcT); } while ((unsigned)(v >> 32) != (unsigned)T_);
      tails_s[i] = __uint_as_float((unsigned)v);
    }
    __asm__ volatile("s_waitcnt lgkmcnt(0)" ::: "memory");
    if (ln < O_) {
      float v = bo;
#pragma unroll
      for (int p3 = 0; p3 < 7; ++p3) v += tails_s[p3 * 3 + ln];
      out_net[((size_t)b * (T_ + 1) + T_) * O_ + ln] = v;
    }
  }
}

// ---------------------------------------------------------------------------
// Fallback (ws too small): single-block-per-batch sparse outer-product.
// ---------------------------------------------------------------------------
__global__ __launch_bounds__(1024, 1) void rnn_fallback(
    const float* __restrict__ x, const float* __restrict__ noise,
    const float* __restrict__ W_i2h, const float* __restrict__ b_i2h,
    const float* __restrict__ Wh, const float* __restrict__ b_h2h,
    const float* __restrict__ W_h2o, const float* __restrict__ b_h2o,
    const int* __restrict__ taup, const int* __restrict__ dtp,
    float* __restrict__ out_net, float* __restrict__ out_rnn) {
  __shared__ float2 pair_s[544];
  __shared__ float cb_s[H_];
  __shared__ float w3_s[3 * 416];
  __shared__ float wpart_s[8][3];
  __shared__ int wcnt_s[8];
  __shared__ float x_s[I_];
  __shared__ int cntp_s;
  __align__(16) __shared__ float partial_s[8 * H_];

  const int tid = threadIdx.x;
  const int b = blockIdx.x;
  const int lane = tid & 63;
  const int wave = tid >> 6;
  const int slice = tid >> 7;
  const int j4 = (tid & 127) * 4;

  const float alpha = (float)dtp[0] / (float)taup[0];
  const float nzscale = (float)(sqrt(2.0 * (double)alpha) * 0.01);

  float wi[I_];
  if (tid < H_) {
#pragma unroll
    for (int i = 0; i < I_; ++i) wi[i] = W_i2h[tid * I_ + i];
    cb_s[tid] = b_i2h[tid] + b_h2h[tid];
  }
  for (int idx = tid; idx < O_ * NEX_; idx += 1024) {
    int o = idx / NEX_, e = idx - o * NEX_;
    w3_s[o * 416 + e] = W_h2o[idx];
  }
  const float myb = (tid < O_) ? b_h2o[tid] : 0.f;
  if (tid == 0) cntp_s = 0;
  float* rnn_b = out_rnn + (size_t)b * (T_ + 1) * H_;
  float* net_b = out_net + (size_t)b * (T_ + 1) * O_;
  if (tid < H_) rnn_b[tid] = 0.f;
  if (tid < O_) net_b[tid] = 0.f;
  __syncthreads();

  int cntp = 0;
  for (int t = 0; t < T_; ++t) {
    float nzv = 0.f, xv = 0.f;
    if (tid < H_) nzv = noise[((size_t)b * T_ + t) * H_ + tid];
    if (tid < I_) xv = x[((size_t)b * T_ + t) * I_ + tid];
    float4 acc = {0.f, 0.f, 0.f, 0.f};
    const int iters = cntp >> 3;
    for (int r = 0; r < iters; r += 4) {
#pragma unroll
      for (int u = 0; u < 4; ++u) {
        const float2 p = pair_s[(r + u) * 8 + slice];
        const int k = __float_as_int(p.y);
        acc.x += p.x * Wh[(size_t)(j4 + 0) * H_ + k];
        acc.y += p.x * Wh[(size_t)(j4 + 1) * H_ + k];
        acc.z += p.x * Wh[(size_t)(j4 + 2) * H_ + k];
        acc.w += p.x * Wh[(size_t)(j4 + 3) * H_ + k];
      }
    }
    if (tid < I_) x_s[tid] = xv;
    *reinterpret_cast<float4*>(partial_s + slice * H_ + j4) = acc;
    __syncthreads();
    unsigned long long mask = 0ull;
    float h = 0.f;
    if (tid < H_) {
      float sum = 0.f;
#pragma unroll
      for (int s2 = 0; s2 < 8; ++s2) sum += partial_s[s2 * H_ + tid];
      float xi = 0.f;
#pragma unroll
      for (int i = 0; i < I_; ++i) xi += wi[i] * x_s[i];
      const float pre = alpha * (sum + xi + cb_s[tid]) + nzscale * nzv;
      h = fmaxf(pre, 0.f);
      rnn_b[(size_t)(t + 1) * H_ + tid] = h;
      float p0 = 0.f, p1 = 0.f, p2 = 0.f;
      if (tid >= NIN_) {
        const int e = tid - NIN_;
        p0 = h * w3_s[e];
        p1 = h * w3_s[416 + e];
        p2 = h * w3_s[832 + e];
      }
#pragma unroll
      for (int off = 32; off >= 1; off >>= 1) {
        p0 += __shfl_xor(p0, off, 64);
        p1 += __shfl_xor(p1, off, 64);
        p2 += __shfl_xor(p2, off, 64);
      }
      mask = __ballot(h > 0.f);
      if (lane == 0) {
        wcnt_s[wave] = (int)__popcll(mask);
        wpart_s[wave][0] = p0;
        wpart_s[wave][1] = p1;
        wpart_s[wave][2] = p2;
      }
    }
    __syncthreads();
    if (tid < H_) {
      int base = 0, cnt = 0;
#pragma unroll
      for (int w = 0; w < 8; ++w) {
        const int c = wcnt_s[w];
        if (w < wave) base += c;
        cnt += c;
      }
      if (h > 0.f)
        pair_s[base + (int)__popcll(mask & ((1ull << lane) - 1ull))] =
            make_float2(h, __int_as_float(tid));
      const int cp = (cnt + 31) & ~31;
      if (tid < cp - cnt) pair_s[cnt + tid] = make_float2(0.f, __int_as_float(0));
      if (tid == 0) cntp_s = cp;
      if (tid < O_) {
        float o = myb;
#pragma unroll
        for (int w = 0; w < 8; ++w) o += wpart_s[w][tid];
        net_b[(size_t)(t + 1) * O_ + tid] = o;
      }
    }
    __syncthreads();
    cntp = cntp_s;
  }
}

extern "C" void kernel_launch(void* const* d_in, const int* in_sizes, int n_in,
                              void* d_out, int out_size, void* d_ws,
                              size_t ws_size, hipStream_t stream) {
  const float* x = (const float*)d_in[0];
  const float* noise = (const float*)d_in[1];
  const float* W_i2h = (const float*)d_in[2];
  const float* b_i2h = (const float*)d_in[3];
  const float* W_h2h = (const float*)d_in[4];
  const float* b_h2h = (const float*)d_in[5];
  const float* W_h2o = (const float*)d_in[6];
  const float* b_h2o = (const float*)d_in[7];
  const int* tau = (const int*)d_in[8];
  const int* dt = (const int*)d_in[9];

  float* out_net = (float*)d_out;
  float* out_rnn = (float*)d_out + (size_t)B_ * (T_ + 1) * O_;

  if (d_ws != nullptr && ws_size >= WS_NEED) {
    ull* recs = (ull*)d_ws;
    int* flags = (int*)((char*)d_ws + FLAGS_OFF);
    // zero flags every call (stream-ordered) -> no stale backpressure state
    hipMemsetAsync(flags, 0, B_ * NQ * sizeof(int), stream);
    hipLaunchKernelGGL(rnn8, dim3(B_ * NQ), dim3(1024), 0, stream, x, noise,
                       W_i2h, b_i2h, W_h2h, b_h2h, W_h2o, b_h2o, tau, dt, recs,
                       flags, out_net, out_rnn);
  } else {
    hipLaunchKernelGGL(rnn_fallback, dim3(B_), dim3(1024), 0, stream, x, noise,
                       W_i2h, b_i2h, W_h2h, b_h2h, W_h2o, b_h2o, tau, dt,
                       out_net, out_rnn);
  }
}

// Round 6
// 1433.921 us; speedup vs baseline: 2.2235x; 2.2235x over previous
//
#include <hip/hip_runtime.h>

typedef unsigned long long ull;
typedef _Float16 half2v __attribute__((ext_vector_type(2)));

#define B_ 64
#define T_ 1024
#define I_ 16
#define H_ 512
#define O_ 3
#define NIN_ 103
#define NEX_ 409

#define NQ 8     // blocks per batch cluster (64 rows each)
#define RS 64    // rows per block
#define DEPTH 4  // tag ring depth: data-dependency skew <=1 makes this safe
                 // with NO backpressure flags (slot (t+1)&3 holds tag t-3,
                 // provably consumed by all peers before overwrite)
#define SLOTS 32 // ull slots per (b,d,q): 32x {tag,f16x2 h}
#define REC_BYTES ((size_t)B_ * DEPTH * NQ * SLOTS * 8)  // 512 KB
#define WS_NEED REC_BYTES

#define AL(p) __hip_atomic_load((p), __ATOMIC_RELAXED, __HIP_MEMORY_SCOPE_AGENT)
#define AS(p, v) \
  __hip_atomic_store((p), (v), __ATOMIC_RELAXED, __HIP_MEMORY_SCOPE_AGENT)

__device__ __forceinline__ float dot2(unsigned a, unsigned b, float c) {
  return __builtin_amdgcn_fdot2(__builtin_bit_cast(half2v, a),
                                __builtin_bit_cast(half2v, b), c, false);
}

// ---------------------------------------------------------------------------
// 8-block-per-batch cluster RNN. Block (b,q) owns rows [q*64, q*64+64) of
// W_h2h in 16 VGPRs/thread (f16 pairs). Exchange: tag-in-word 8-B relaxed
// agent atomics into a DEPTH-4 ring -> exactly ONE L3 round trip (store ->
// poll) per step on the critical path; no flags, no fences, no sleeps.
// recs is zeroed each call (stream-ordered memset) so tags never alias.
// 512 blocks x 1024 thr = 2 blocks/CU co-resident by thread capacity.
// ---------------------------------------------------------------------------
__global__ __launch_bounds__(1024, 8) void rnn8(
    const float* __restrict__ x, const float* __restrict__ noise,
    const float* __restrict__ W_i2h, const float* __restrict__ b_i2h,
    const float* __restrict__ W_h2h, const float* __restrict__ b_h2h,
    const int* __restrict__ taup, const int* __restrict__ dtp,
    ull* __restrict__ recs, float* __restrict__ out_rnn) {
  __shared__ unsigned h_lds[H_ / 2];    // h(t) as f16x2 words
  __shared__ float partial_s[16 * RS];  // [wave][row]
  __shared__ float wi2h_s[RS * 17];     // padded W_i2h rows
  __shared__ float bias_s[RS];          // b_i2h + b_h2h
  __shared__ float x_s[I_];
  __shared__ float xi_s[RS];

  const int tid = threadIdx.x;
  const int g = blockIdx.x;
  const int b = (g >> 6) * 8 + (g & 7);  // cluster blocks share g&7 (XCD)
  const int q = (g >> 3) & 7;
  const int wv = tid >> 6, ln = tid & 63;
  const int row0 = q * RS;

  const float alpha = (float)dtp[0] / (float)taup[0];
  const float nzscale = (float)(sqrt(2.0 * (double)alpha) * 0.01);

  // ---- W_h2h slice -> 16 VGPRs/thread (row ln, k in [wv*32, wv*32+32)) ----
  unsigned wreg[16];
  {
    const float* wrow = W_h2h + (size_t)(row0 + ln) * H_ + wv * 32;
#pragma unroll
    for (int i = 0; i < 8; ++i) {
      const float4 f = ((const float4*)wrow)[i];
      half2v lo = {(_Float16)f.x, (_Float16)f.y};
      half2v hi = {(_Float16)f.z, (_Float16)f.w};
      wreg[2 * i] = __builtin_bit_cast(unsigned, lo);
      wreg[2 * i + 1] = __builtin_bit_cast(unsigned, hi);
    }
  }
  // ---- other setup ----
  {
    const int l = tid >> 4, i = tid & 15;  // 1024 = 64 rows x 16
    wi2h_s[l * 17 + i] = W_i2h[(size_t)(row0 + l) * I_ + i];
  }
  if (tid < RS) bias_s[tid] = b_i2h[row0 + tid] + b_h2h[row0 + tid];
  if (tid < H_ / 2) h_lds[tid] = 0u;
  if (tid < RS) out_rnn[(size_t)b * (T_ + 1) * H_ + row0 + tid] = 0.f;
  __syncthreads();

  const size_t xrow = (size_t)b * T_ * I_;
  const size_t nrow = (size_t)b * T_ * H_ + row0;
  const int pollp = wv >> 1;            // chunk this wave stages
  const bool dopoll = (pollp != q);     // own chunk is local (wave 0 writes)

  float nzv = 0.f;
  for (int t = 0; t < T_; ++t) {
    // ---------- prologue: per-step loads + tag-polls ----------
    if (wv == 0) nzv = noise[nrow + (size_t)t * H_ + ln];
    if (wv == 2 * q + 1) {  // own-chunk wave: x load + xi (never polls)
      if (ln < I_) x_s[ln] = x[xrow + (size_t)t * I_ + ln];
      __asm__ volatile("s_waitcnt vmcnt(0) lgkmcnt(0)" ::: "memory");
      float a = bias_s[ln];
#pragma unroll
      for (int i = 0; i < I_; ++i) a += wi2h_s[ln * 17 + i] * x_s[i];
      xi_s[ln] = a;
    }
    if (t > 0 && dopoll && ln < 16) {
      const ull* src = recs +
                       ((size_t)(b * DEPTH + (t & 3)) * NQ + pollp) * SLOTS +
                       (wv & 1) * 16 + ln;
      ull v;
      do { v = AL(src); } while ((unsigned)(v >> 32) != (unsigned)t);
      h_lds[wv * 16 + ln] = (unsigned)v;
    }
    __syncthreads();  // A: h(t) staged

    // ---------- GEMV: dot2 from W-regs, h broadcast from LDS ----------
    float acc = 0.f;
    const unsigned* hw = &h_lds[wv * 16];
#pragma unroll
    for (int i4 = 0; i4 < 4; ++i4) {
      const uint4 hv = ((const uint4*)hw)[i4];
      acc = dot2(wreg[i4 * 4 + 0], hv.x, acc);
      acc = dot2(wreg[i4 * 4 + 1], hv.y, acc);
      acc = dot2(wreg[i4 * 4 + 2], hv.z, acc);
      acc = dot2(wreg[i4 * 4 + 3], hv.w, acc);
    }
    partial_s[wv * RS + ln] = acc;
    __syncthreads();  // B: partials ready

    // ---------- epilogue (wave 0): h, publish ----------
    if (wv == 0) {
      float sum = 0.f;
#pragma unroll
      for (int w2 = 0; w2 < 16; ++w2) sum += partial_s[w2 * RS + ln];
      const float pre = alpha * (sum + xi_s[ln]) + nzscale * nzv;
      const float h = fmaxf(pre, 0.f);
      out_rnn[((size_t)b * (T_ + 1) + t + 1) * H_ + row0 + ln] = h;
      // pack f16x2 via shuffles (no LDS round trip before the stores)
      const unsigned hu =
          (unsigned)__builtin_bit_cast(unsigned short, (_Float16)h);
      const unsigned lo = __shfl(hu, 2 * ln, 64);
      const unsigned hi = __shfl(hu, 2 * ln + 1, 64);
      if (ln < 32) {
        const unsigned word = lo | (hi << 16);
        h_lds[q * 32 + ln] = word;  // own chunk for next GEMV
        ull* dst =
            recs + ((size_t)(b * DEPTH + ((t + 1) & 3)) * NQ + q) * SLOTS + ln;
        AS(dst, (((ull)(unsigned)(t + 1)) << 32) | (ull)word);
      }
    }
  }
}

// ---------------------------------------------------------------------------
// Post-pass: out_net[b][t] = W_h2o . h_ex(b,t) + b_h2o (t>=1), zeros at t=0.
// One wave per (b,t); memory-bound re-read of out_rnn (~134 MB, ~30 us).
// ---------------------------------------------------------------------------
__global__ __launch_bounds__(256) void h2o_kernel(
    const float* __restrict__ out_rnn, const float* __restrict__ W_h2o,
    const float* __restrict__ b_h2o, float* __restrict__ out_net) {
  __shared__ float w3[3 * 416];
  const int tid = threadIdx.x;
  for (int idx = tid; idx < O_ * NEX_; idx += 256) {
    const int o = idx / NEX_, e = idx - o * NEX_;
    w3[o * 416 + e] = W_h2o[idx];
  }
  __syncthreads();
  const int wv = tid >> 6, ln = tid & 63;
  const int task = blockIdx.x * 4 + wv;
  if (task >= B_ * (T_ + 1)) return;
  const int bb = task / (T_ + 1), t = task - bb * (T_ + 1);
  float* dst = out_net + (size_t)task * O_;
  if (t == 0) {
    if (ln < O_) dst[ln] = 0.f;
    return;
  }
  const float* hrow = out_rnn + (size_t)task * H_ + NIN_;
  float a0 = 0.f, a1 = 0.f, a2 = 0.f;
  for (int k = ln; k < NEX_; k += 64) {
    const float hv = hrow[k];
    a0 += hv * w3[k];
    a1 += hv * w3[416 + k];
    a2 += hv * w3[832 + k];
  }
#pragma unroll
  for (int off = 32; off >= 1; off >>= 1) {
    a0 += __shfl_xor(a0, off, 64);
    a1 += __shfl_xor(a1, off, 64);
    a2 += __shfl_xor(a2, off, 64);
  }
  if (ln == 0) {
    dst[0] = a0 + b_h2o[0];
    dst[1] = a1 + b_h2o[1];
    dst[2] = a2 + b_h2o[2];
  }
}

// ---------------------------------------------------------------------------
// Fallback (ws too small): single-block-per-batch sparse outer-product.
// ---------------------------------------------------------------------------
__global__ __launch_bounds__(1024, 1) void rnn_fallback(
    const float* __restrict__ x, const float* __restrict__ noise,
    const float* __restrict__ W_i2h, const float* __restrict__ b_i2h,
    const float* __restrict__ Wh, const float* __restrict__ b_h2h,
    const float* __restrict__ W_h2o, const float* __restrict__ b_h2o,
    const int* __restrict__ taup, const int* __restrict__ dtp,
    float* __restrict__ out_net, float* __restrict__ out_rnn) {
  __shared__ float2 pair_s[544];
  __shared__ float cb_s[H_];
  __shared__ float w3_s[3 * 416];
  __shared__ float wpart_s[8][3];
  __shared__ int wcnt_s[8];
  __shared__ float x_s[I_];
  __shared__ int cntp_s;
  __align__(16) __shared__ float partial_s[8 * H_];

  const int tid = threadIdx.x;
  const int b = blockIdx.x;
  const int lane = tid & 63;
  const int wave = tid >> 6;
  const int slice = tid >> 7;
  const int j4 = (tid & 127) * 4;

  const float alpha = (float)dtp[0] / (float)taup[0];
  const float nzscale = (float)(sqrt(2.0 * (double)alpha) * 0.01);

  float wi[I_];
  if (tid < H_) {
#pragma unroll
    for (int i = 0; i < I_; ++i) wi[i] = W_i2h[tid * I_ + i];
    cb_s[tid] = b_i2h[tid] + b_h2h[tid];
  }
  for (int idx = tid; idx < O_ * NEX_; idx += 1024) {
    int o = idx / NEX_, e = idx - o * NEX_;
    w3_s[o * 416 + e] = W_h2o[idx];
  }
  const float myb = (tid < O_) ? b_h2o[tid] : 0.f;
  if (tid == 0) cntp_s = 0;
  float* rnn_b = out_rnn + (size_t)b * (T_ + 1) * H_;
  float* net_b = out_net + (size_t)b * (T_ + 1) * O_;
  if (tid < H_) rnn_b[tid] = 0.f;
  if (tid < O_) net_b[tid] = 0.f;
  __syncthreads();

  int cntp = 0;
  for (int t = 0; t < T_; ++t) {
    float nzv = 0.f, xv = 0.f;
    if (tid < H_) nzv = noise[((size_t)b * T_ + t) * H_ + tid];
    if (tid < I_) xv = x[((size_t)b * T_ + t) * I_ + tid];
    float4 acc = {0.f, 0.f, 0.f, 0.f};
    const int iters = cntp >> 3;
    for (int r = 0; r < iters; r += 4) {
#pragma unroll
      for (int u = 0; u < 4; ++u) {
        const float2 p = pair_s[(r + u) * 8 + slice];
        const int k = __float_as_int(p.y);
        acc.x += p.x * Wh[(size_t)(j4 + 0) * H_ + k];
        acc.y += p.x * Wh[(size_t)(j4 + 1) * H_ + k];
        acc.z += p.x * Wh[(size_t)(j4 + 2) * H_ + k];
        acc.w += p.x * Wh[(size_t)(j4 + 3) * H_ + k];
      }
    }
    if (tid < I_) x_s[tid] = xv;
    *reinterpret_cast<float4*>(partial_s + slice * H_ + j4) = acc;
    __syncthreads();
    unsigned long long mask = 0ull;
    float h = 0.f;
    if (tid < H_) {
      float sum = 0.f;
#pragma unroll
      for (int s2 = 0; s2 < 8; ++s2) sum += partial_s[s2 * H_ + tid];
      float xi = 0.f;
#pragma unroll
      for (int i = 0; i < I_; ++i) xi += wi[i] * x_s[i];
      const float pre = alpha * (sum + xi + cb_s[tid]) + nzscale * nzv;
      h = fmaxf(pre, 0.f);
      rnn_b[(size_t)(t + 1) * H_ + tid] = h;
      float p0 = 0.f, p1 = 0.f, p2 = 0.f;
      if (tid >= NIN_) {
        const int e = tid - NIN_;
        p0 = h * w3_s[e];
        p1 = h * w3_s[416 + e];
        p2 = h * w3_s[832 + e];
      }
#pragma unroll
      for (int off = 32; off >= 1; off >>= 1) {
        p0 += __shfl_xor(p0, off, 64);
        p1 += __shfl_xor(p1, off, 64);
        p2 += __shfl_xor(p2, off, 64);
      }
      mask = __ballot(h > 0.f);
      if (lane == 0) {
        wcnt_s[wave] = (int)__popcll(mask);
        wpart_s[wave][0] = p0;
        wpart_s[wave][1] = p1;
        wpart_s[wave][2] = p2;
      }
    }
    __syncthreads();
    if (tid < H_) {
      int base = 0, cnt = 0;
#pragma unroll
      for (int w = 0; w < 8; ++w) {
        const int c = wcnt_s[w];
        if (w < wave) base += c;
        cnt += c;
      }
      if (h > 0.f)
        pair_s[base + (int)__popcll(mask & ((1ull << lane) - 1ull))] =
            make_float2(h, __int_as_float(tid));
      const int cp = (cnt + 31) & ~31;
      if (tid < cp - cnt) pair_s[cnt + tid] = make_float2(0.f, __int_as_float(0));
      if (tid == 0) cntp_s = cp;
      if (tid < O_) {
        float o = myb;
#pragma unroll
        for (int w = 0; w < 8; ++w) o += wpart_s[w][tid];
        net_b[(size_t)(t + 1) * O_ + tid] = o;
      }
    }
    __syncthreads();
    cntp = cntp_s;
  }
}

extern "C" void kernel_launch(void* const* d_in, const int* in_sizes, int n_in,
                              void* d_out, int out_size, void* d_ws,
                              size_t ws_size, hipStream_t stream) {
  const float* x = (const float*)d_in[0];
  const float* noise = (const float*)d_in[1];
  const float* W_i2h = (const float*)d_in[2];
  const float* b_i2h = (const float*)d_in[3];
  const float* W_h2h = (const float*)d_in[4];
  const float* b_h2h = (const float*)d_in[5];
  const float* W_h2o = (const float*)d_in[6];
  const float* b_h2o = (const float*)d_in[7];
  const int* tau = (const int*)d_in[8];
  const int* dt = (const int*)d_in[9];

  float* out_net = (float*)d_out;
  float* out_rnn = (float*)d_out + (size_t)B_ * (T_ + 1) * O_;

  if (d_ws != nullptr && ws_size >= WS_NEED) {
    ull* recs = (ull*)d_ws;
    // zero all tags every call (stream-ordered): no stale/poison tag aliasing
    hipMemsetAsync(recs, 0, REC_BYTES, stream);
    hipLaunchKernelGGL(rnn8, dim3(B_ * NQ), dim3(1024), 0, stream, x, noise,
                       W_i2h, b_i2h, W_h2h, b_h2h, tau, dt, recs, out_rnn);
    hipLaunchKernelGGL(h2o_kernel, dim3((B_ * (T_ + 1) + 3) / 4), dim3(256), 0,
                       stream, out_rnn, W_h2o, b_h2o, out_net);
  } else {
    hipLaunchKernelGGL(rnn_fallback, dim3(B_), dim3(1024), 0, stream, x, noise,
                       W_i2h, b_i2h, W_h2h, b_h2h, W_h2o, b_h2o, tau, dt,
                       out_net, out_rnn);
  }
}